// Round 2
// baseline (571.729 us; speedup 1.0000x reference)
//
#include <hip/hip_runtime.h>
#include <hip/hip_bf16.h>

// Problem: B=32, S=2048, D=1024, SIZE=1024
//   term1[b,s,k] = sum_d WO[k,d]*inputs[b,s,d]   (GEMM M=65536,N=1024,K=1024)
//   term2[b,k]   = sum_d WG[k,d]*g[b,d]
//   out[b,s]     = sum_k v[k]*tanh(term1+term2)
#define BB   32
#define SS   2048
#define DD   1024
#define SZ   1024
#define MM   (BB*SS)   // 65536

typedef short bf16x8 __attribute__((ext_vector_type(8)));
typedef float f32x4  __attribute__((ext_vector_type(4)));

__device__ __forceinline__ unsigned short f2bf(float x) {
    // round-to-nearest-even fp32 -> bf16 (inputs are finite normals)
    unsigned u = __float_as_uint(x);
    u += 0x7fffu + ((u >> 16) & 1u);
    return (unsigned short)(u >> 16);
}
__device__ __forceinline__ unsigned pack2_bf16(float a, float b) {
    return (unsigned)f2bf(a) | ((unsigned)f2bf(b) << 16);
}

__device__ __forceinline__ float ftanh(float x) {
    // tanh(x) = 1 - 2/(exp(2x)+1); saturates correctly for large |x|
    float e = __expf(2.0f * x);
    return 1.0f - 2.0f / (e + 1.0f);
}

// ---------------- prep: WO fp32 -> bf16, term2 = WG @ g[b] (fp32) -----------
__global__ void prep_kernel(const float* __restrict__ WO,
                            const float* __restrict__ WG,
                            const float* __restrict__ g,
                            unsigned short* __restrict__ WOb,
                            float* __restrict__ term2) {
    __shared__ float gs[DD];
    int bid = blockIdx.x, tid = threadIdx.x;
    if (bid < 1024) {
        // convert 1024 floats of WO per block
        int base = bid * 1024 + tid * 4;
        float4 w = *(const float4*)(WO + base);
        unsigned p0 = pack2_bf16(w.x, w.y), p1 = pack2_bf16(w.z, w.w);
        *(uint2*)&WOb[base] = make_uint2(p0, p1);
    } else {
        int id = bid - 1024;           // 0..127
        int b  = id >> 2;              // batch
        int k  = ((id & 3) << 8) + tid;
        #pragma unroll
        for (int r = 0; r < 4; r++) gs[r * 256 + tid] = g[b * DD + r * 256 + tid];
        __syncthreads();
        const float* wr = WG + (size_t)k * DD;
        float s = 0.f;
        #pragma unroll 4
        for (int d = 0; d < DD; d += 4) {
            float4 wv = *(const float4*)(wr + d);
            s += wv.x * gs[d] + wv.y * gs[d + 1] + wv.z * gs[d + 2] + wv.w * gs[d + 3];
        }
        term2[b * SZ + k] = s;
    }
}

// ---------------- main: fused GEMM + tanh + v-reduction ---------------------
// block tile 128(M) x 256(N), BK=32; 4 waves, each 64x128 (4x8 of 16x16x32)
__global__ __launch_bounds__(256, 2) void fused_main(
    const float* __restrict__ Ain,            // [MM, DD] fp32
    const unsigned short* __restrict__ WOb,   // [SZ, DD] bf16
    const float* __restrict__ term2,          // [BB, SZ] fp32
    const float* __restrict__ v,              // [SZ] fp32
    float* __restrict__ out) {                // [MM] fp32 (pre-zeroed)
    __shared__ unsigned short Asm[128 * 40];  // rows padded 32->40 bf16 (80B): A-frag reads 2-way only
    __shared__ unsigned short Bsm[256 * 32];  // m97 layout (global_load_lds forces contiguity)
    __shared__ float part[2][128];

    const int tid  = threadIdx.x;
    const int wave = tid >> 6;
    const int lane = tid & 63;
    const int wm = wave & 1, wn = wave >> 1;
    const int l15 = lane & 15;
    const int k8  = lane >> 4;

    const int bid   = blockIdx.x;
    const int ntile = bid & 3;        // adjacent blocks share m-tile -> LLC reuse of A
    const int mtile = bid >> 2;
    const int m0 = mtile * 128;
    const int n0 = ntile * 256;
    const int bidx = m0 >> 11;        // batch index (128 | 2048)

    f32x4 acc[4][8];
    #pragma unroll
    for (int i = 0; i < 4; i++)
        #pragma unroll
        for (int j = 0; j < 8; j++) acc[i][j] = (f32x4){0.f, 0.f, 0.f, 0.f};

    for (int k0 = 0; k0 < DD; k0 += 32) {
        // B tile 256x32 bf16 (16 KB) via async global->LDS, 16B/lane
        #pragma unroll
        for (int r = 0; r < 4; r++) {
            int chunk = r * 256 + tid;
            int n = chunk >> 2, ks = chunk & 3;
            const unsigned short* src = WOb + (size_t)(n0 + n) * DD + k0 + ks * 8;
            __builtin_amdgcn_global_load_lds(
                (const __attribute__((address_space(1))) void*)src,
                (__attribute__((address_space(3))) void*)(&Bsm[chunk * 8]),
                16, 0, 0);
        }
        // A tile 128x32 fp32 -> bf16 (VGPR round-trip; fp32 source forces it)
        #pragma unroll
        for (int r = 0; r < 4; r++) {
            int e = r * 256 + tid;
            int row = e >> 3, qc = e & 7;
            float4 av = *(const float4*)(Ain + (size_t)(m0 + row) * DD + k0 + qc * 4);
            unsigned p0 = pack2_bf16(av.x, av.y), p1 = pack2_bf16(av.z, av.w);
            *(uint2*)&Asm[row * 40 + qc * 4] = make_uint2(p0, p1);
        }
        __syncthreads();

        bf16x8 afr[4], bfr[8];
        #pragma unroll
        for (int mi = 0; mi < 4; mi++)
            afr[mi] = *(const bf16x8*)&Asm[(wm * 64 + mi * 16 + l15) * 40 + k8 * 8];
        #pragma unroll
        for (int ni = 0; ni < 8; ni++)
            bfr[ni] = *(const bf16x8*)&Bsm[(wn * 128 + ni * 16 + l15) * 32 + k8 * 8];
        #pragma unroll
        for (int ni = 0; ni < 8; ni++)
            #pragma unroll
            for (int mi = 0; mi < 4; mi++)
                acc[mi][ni] = __builtin_amdgcn_mfma_f32_16x16x32_bf16(
                    afr[mi], bfr[ni], acc[mi][ni], 0, 0, 0);
        __syncthreads();
    }

    // epilogue: tanh(term1+term2)*v, reduce over this block's 256 n-columns
    float rsum[4][4];
    #pragma unroll
    for (int mi = 0; mi < 4; mi++)
        #pragma unroll
        for (int r = 0; r < 4; r++) rsum[mi][r] = 0.f;

    #pragma unroll
    for (int ni = 0; ni < 8; ni++) {
        int gn = n0 + wn * 128 + ni * 16 + l15;   // C/D: col = lane&15
        float t2 = term2[bidx * SZ + gn];
        float vv = v[gn];
        #pragma unroll
        for (int mi = 0; mi < 4; mi++)
            #pragma unroll
            for (int r = 0; r < 4; r++)
                rsum[mi][r] += ftanh(acc[mi][ni][r] + t2) * vv;
    }
    // reduce across the 16 col-lanes (butterfly within 16-lane groups)
    #pragma unroll
    for (int mi = 0; mi < 4; mi++)
        #pragma unroll
        for (int r = 0; r < 4; r++) {
            float s = rsum[mi][r];
            s += __shfl_xor(s, 1, 16);
            s += __shfl_xor(s, 2, 16);
            s += __shfl_xor(s, 4, 16);
            s += __shfl_xor(s, 8, 16);
            rsum[mi][r] = s;
        }
    // lane l15 == mi*4+r publishes row (wm*64 + mi*16 + k8*4 + r)
    float val = 0.f;
    #pragma unroll
    for (int mi = 0; mi < 4; mi++)
        #pragma unroll
        for (int r = 0; r < 4; r++)
            if (l15 == mi * 4 + r) val = rsum[mi][r];
    {
        int mi = l15 >> 2, r = l15 & 3;
        part[wn][wm * 64 + mi * 16 + k8 * 4 + r] = val;
    }
    __syncthreads();
    if (tid < 128) atomicAdd(&out[m0 + tid], part[0][tid] + part[1][tid]);
}

extern "C" void kernel_launch(void* const* d_in, const int* in_sizes, int n_in,
                              void* d_out, int out_size, void* d_ws, size_t ws_size,
                              hipStream_t stream) {
    const float* inputs = (const float*)d_in[0];   // [32,2048,1024]
    const float* g      = (const float*)d_in[1];   // [32,1024]
    const float* WO     = (const float*)d_in[2];   // [1024,1024]
    const float* WG     = (const float*)d_in[3];   // [1024,1024]
    const float* v      = (const float*)d_in[4];   // [1,1024]
    float* out = (float*)d_out;

    unsigned short* WOb = (unsigned short*)d_ws;                       // 2 MB bf16 WO
    float* term2 = (float*)((char*)d_ws + (size_t)SZ * DD * 2);        // 128 KB fp32

    (void)hipMemsetAsync(d_out, 0, sizeof(float) * MM, stream);
    prep_kernel<<<1024 + 128, 256, 0, stream>>>(WO, WG, g, WOb, term2);
    fused_main<<<(MM / 128) * (SZ / 256), 256, 0, stream>>>(inputs, WOb, term2, v, out);
}